// Round 2
// baseline (530.441 us; speedup 1.0000x reference)
//
#include <hip/hip_runtime.h>
#include <hip/hip_bf16.h>
#include <stdint.h>

// B=4 S=2048 D=1024 H=2048 E=8 ; T = 8192 tokens, top-1 MoE.
// Inputs are FLOAT32 (reference dtype); output FLOAT32. Compute in bf16 MFMA.
// Pipeline: router(fp32) -> scan -> scatter -> cvt x->bf16 ->
// transpose+cvt W1,W2 -> gemm1(bf16,relu) -> gemm2(bf16, scale+scatter, f32 store)

typedef unsigned short bf16_t;
typedef short short8 __attribute__((ext_vector_type(8)));
typedef float f32x4 __attribute__((ext_vector_type(4)));

#define T_TOK 8192
#define DDIM 1024
#define HDIM 2048
#define NEXP 8
#define MAXTILES 72   // sum ceil(count_e/128) <= (8192 + 8*127)/128 = 71

__device__ __forceinline__ bf16_t f2b(float f) {
    unsigned int x = __builtin_bit_cast(unsigned int, f);
    unsigned int r = x + 0x7fffu + ((x >> 16) & 1u);   // RNE
    return (bf16_t)(r >> 16);
}
__device__ __forceinline__ void gld_lds16(const bf16_t* src, bf16_t* dst) {
    // per-lane global src, wave-uniform LDS base; lane writes at dst + lane*16B
    __builtin_amdgcn_global_load_lds((const __attribute__((address_space(1))) void*)src,
                                     (__attribute__((address_space(3))) void*)dst, 16, 0, 0);
}

// ---------------- router: one wave per token (fp32) ----------------
__global__ __launch_bounds__(256) void router_kernel(
    const float* __restrict__ x, const float* __restrict__ Wr,
    const float* __restrict__ br, int* __restrict__ expert_id,
    float* __restrict__ gate, int* __restrict__ counts) {
    int wave = threadIdx.x >> 6, lane = threadIdx.x & 63;
    int t = blockIdx.x * 4 + wave;
    const float* xt = x + (size_t)t * DDIM + lane * 16;
    float xv[16];
#pragma unroll
    for (int q = 0; q < 4; q++) {
        float4 f = *(const float4*)(xt + q * 4);
        xv[q * 4 + 0] = f.x; xv[q * 4 + 1] = f.y;
        xv[q * 4 + 2] = f.z; xv[q * 4 + 3] = f.w;
    }
    float acc[NEXP];
#pragma unroll
    for (int e = 0; e < NEXP; e++) acc[e] = 0.f;
#pragma unroll
    for (int i = 0; i < 16; i++) {
        const float* wr = Wr + (size_t)(lane * 16 + i) * NEXP;
#pragma unroll
        for (int e = 0; e < NEXP; e++) acc[e] += xv[i] * wr[e];
    }
#pragma unroll
    for (int off = 32; off; off >>= 1)
#pragma unroll
        for (int e = 0; e < NEXP; e++) acc[e] += __shfl_xor(acc[e], off);
    if (lane == 0) {
        float l[NEXP];
#pragma unroll
        for (int e = 0; e < NEXP; e++) l[e] = acc[e] + br[e];
        int best = 0; float bm = l[0];
#pragma unroll
        for (int e = 1; e < NEXP; e++) if (l[e] > bm) { bm = l[e]; best = e; }
        float s = 0.f;
#pragma unroll
        for (int e = 0; e < NEXP; e++) s += __expf(l[e] - bm);
        expert_id[t] = best;
        gate[t] = 1.0f / s;      // softmax prob of the argmax expert
        atomicAdd(&counts[best], 1);
    }
}

// ---------------- scan: 128-aligned segment offsets + tile->expert map ----------------
__global__ __launch_bounds__(64) void scan_kernel(const int* __restrict__ counts,
                                                  int* __restrict__ pad_off,
                                                  int* __restrict__ tile_expert) {
    if (threadIdx.x == 0) {
        int rowoff = 0, t = 0;
        for (int e = 0; e < NEXP; e++) {
            pad_off[e] = rowoff;
            int nt = (counts[e] + 127) >> 7;
            rowoff += nt << 7;
            for (int i = 0; i < nt; i++) tile_expert[t++] = e;
        }
        while (t < MAXTILES) tile_expert[t++] = -1;
    }
}

// ---------------- scatter: build row->token maps ----------------
__global__ __launch_bounds__(256) void scatter_kernel(
    const int* __restrict__ expert_id, const float* __restrict__ gate,
    const int* __restrict__ pad_off, int* __restrict__ cursor,
    int* __restrict__ tok_of_row, float* __restrict__ gate_of_row) {
    int t = blockIdx.x * 256 + threadIdx.x;
    int e = expert_id[t];
    int p = atomicAdd(&cursor[e], 1);
    int row = pad_off[e] + p;
    tok_of_row[row] = t;
    gate_of_row[row] = gate[t];
}

// ---------------- cvt: fp32 -> bf16, 8 elems/thread ----------------
__global__ __launch_bounds__(256) void cvt_kernel(const float* __restrict__ in,
                                                  bf16_t* __restrict__ out) {
    size_t i = ((size_t)blockIdx.x * 256 + threadIdx.x) * 8;
    float4 a = *(const float4*)(in + i);
    float4 b = *(const float4*)(in + i + 4);
    bf16_t tmp[8] = {f2b(a.x), f2b(a.y), f2b(a.z), f2b(a.w),
                     f2b(b.x), f2b(b.y), f2b(b.z), f2b(b.w)};
    *(uint4*)(out + i) = *(uint4*)tmp;
}

// ---------------- fp32 -> bf16 tiled transpose: in [z][R][C] -> out [z][C][R] ----------------
__global__ __launch_bounds__(256) void transpose_kernel(const float* __restrict__ in,
                                                        bf16_t* __restrict__ out,
                                                        int R, int C) {
    __shared__ bf16_t tile[64][72];   // +8 pad: rows stay 16B-aligned, no pow2 bank stride
    int z = blockIdx.z;
    const float* inp = in + (size_t)z * R * C;
    bf16_t* outp = out + (size_t)z * R * C;
    int r0 = blockIdx.y * 64, c0 = blockIdx.x * 64;
    int tid = threadIdx.x;
#pragma unroll
    for (int v = tid; v < 1024; v += 256) {     // 64x64 floats, 4/thread-iter
        int r = v >> 4, c = (v & 15) * 4;
        float4 f = *(const float4*)(inp + (size_t)(r0 + r) * C + c0 + c);
        tile[r][c + 0] = f2b(f.x); tile[r][c + 1] = f2b(f.y);
        tile[r][c + 2] = f2b(f.z); tile[r][c + 3] = f2b(f.w);
    }
    __syncthreads();
#pragma unroll
    for (int v = tid; v < 512; v += 256) {
        int c = v >> 3, r = (v & 7) * 8;
        bf16_t tmp[8];
#pragma unroll
        for (int i = 0; i < 8; i++) tmp[i] = tile[r + i][c];
        *(uint4*)(outp + (size_t)(c0 + c) * R + r0 + r) = *(uint4*)tmp;
    }
}

// ---------------- GEMM1: h[row][H] = relu(xbf[tok[row]] @ W1t[e]^T + b1[e]) ----------------
// W1t: [E][H][D] (K-contiguous rows). grid (H/128, MAXTILES), block 256.
__global__ __launch_bounds__(256) void gemm1_kernel(
    const bf16_t* __restrict__ x, const bf16_t* __restrict__ W1t,
    const float* __restrict__ b1, const int* __restrict__ tile_expert,
    const int* __restrict__ tok_of_row, bf16_t* __restrict__ hbuf) {
    constexpr int K = DDIM, N = HDIM;
    int tile_n = blockIdx.x, tile_m = blockIdx.y;
    int e = tile_expert[tile_m];
    if (e < 0) return;
    __shared__ bf16_t lA[128 * 64];
    __shared__ bf16_t lB[128 * 64];
    int tid = threadIdx.x, wave = tid >> 6, lane = tid & 63;
    const bf16_t* asrc[4]; const bf16_t* bsrc[4];
#pragma unroll
    for (int c = 0; c < 4; c++) {
        int rr = wave * 32 + c * 8 + (lane >> 3);
        int tok = tok_of_row[tile_m * 128 + rr];
        if (tok < 0) tok = 0;   // padded row: read any valid row; store masked in gemm2
        asrc[c] = x + (size_t)tok * K + (lane & 7) * 8;
        bsrc[c] = W1t + (size_t)e * N * K + (size_t)(tile_n * 128 + rr) * K + (lane & 7) * 8;
    }
    f32x4 acc[4][4];
#pragma unroll
    for (int i = 0; i < 4; i++)
#pragma unroll
        for (int j = 0; j < 4; j++) acc[i][j] = {0.f, 0.f, 0.f, 0.f};
    int wm = wave >> 1, wn = wave & 1;
    int lm = lane & 15, quad = lane >> 4;
    for (int k0 = 0; k0 < K; k0 += 64) {
        __syncthreads();
#pragma unroll
        for (int c = 0; c < 4; c++) {
            gld_lds16(asrc[c] + k0, &lA[(wave * 32 + c * 8) * 64]);
            gld_lds16(bsrc[c] + k0, &lB[(wave * 32 + c * 8) * 64]);
        }
        __syncthreads();
#pragma unroll
        for (int kk = 0; kk < 2; kk++) {
            short8 a[4], b[4];
#pragma unroll
            for (int i = 0; i < 4; i++)
                a[i] = *(const short8*)&lA[(wm * 64 + i * 16 + lm) * 64 + kk * 32 + quad * 8];
#pragma unroll
            for (int j = 0; j < 4; j++)
                b[j] = *(const short8*)&lB[(wn * 64 + j * 16 + lm) * 64 + kk * 32 + quad * 8];
#pragma unroll
            for (int i = 0; i < 4; i++)
#pragma unroll
                for (int j = 0; j < 4; j++)
                    acc[i][j] = __builtin_amdgcn_mfma_f32_16x16x32_bf16(a[i], b[j], acc[i][j], 0, 0, 0);
        }
    }
#pragma unroll
    for (int j = 0; j < 4; j++) {
        int col = tile_n * 128 + wn * 64 + j * 16 + lm;
        float bias = b1[e * N + col];
#pragma unroll
        for (int i = 0; i < 4; i++)
#pragma unroll
            for (int r = 0; r < 4; r++) {
                int row = tile_m * 128 + wm * 64 + i * 16 + quad * 4 + r;
                float v = acc[i][j][r] + bias;
                hbuf[(size_t)row * N + col] = f2b(fmaxf(v, 0.f));
            }
    }
}

// ---------------- GEMM2: out[tok[row]] = (h[row] @ W2t[e]^T + b2[e]) * gate[row] ----------------
// W2t: [E][D][H]. grid (D/128, MAXTILES), block 256. out is FLOAT32.
__global__ __launch_bounds__(256) void gemm2_kernel(
    const bf16_t* __restrict__ hbuf, const bf16_t* __restrict__ W2t,
    const float* __restrict__ b2, const int* __restrict__ tile_expert,
    const int* __restrict__ tok_of_row, const float* __restrict__ gate_of_row,
    float* __restrict__ out) {
    constexpr int K = HDIM, N = DDIM;
    int tile_n = blockIdx.x, tile_m = blockIdx.y;
    int e = tile_expert[tile_m];
    if (e < 0) return;
    __shared__ bf16_t lA[128 * 64];
    __shared__ bf16_t lB[128 * 64];
    int tid = threadIdx.x, wave = tid >> 6, lane = tid & 63;
    const bf16_t* asrc[4]; const bf16_t* bsrc[4];
#pragma unroll
    for (int c = 0; c < 4; c++) {
        int rr = wave * 32 + c * 8 + (lane >> 3);
        asrc[c] = hbuf + (size_t)(tile_m * 128 + rr) * K + (lane & 7) * 8;
        bsrc[c] = W2t + (size_t)e * N * K + (size_t)(tile_n * 128 + rr) * K + (lane & 7) * 8;
    }
    f32x4 acc[4][4];
#pragma unroll
    for (int i = 0; i < 4; i++)
#pragma unroll
        for (int j = 0; j < 4; j++) acc[i][j] = {0.f, 0.f, 0.f, 0.f};
    int wm = wave >> 1, wn = wave & 1;
    int lm = lane & 15, quad = lane >> 4;
    for (int k0 = 0; k0 < K; k0 += 64) {
        __syncthreads();
#pragma unroll
        for (int c = 0; c < 4; c++) {
            gld_lds16(asrc[c] + k0, &lA[(wave * 32 + c * 8) * 64]);
            gld_lds16(bsrc[c] + k0, &lB[(wave * 32 + c * 8) * 64]);
        }
        __syncthreads();
#pragma unroll
        for (int kk = 0; kk < 2; kk++) {
            short8 a[4], b[4];
#pragma unroll
            for (int i = 0; i < 4; i++)
                a[i] = *(const short8*)&lA[(wm * 64 + i * 16 + lm) * 64 + kk * 32 + quad * 8];
#pragma unroll
            for (int j = 0; j < 4; j++)
                b[j] = *(const short8*)&lB[(wn * 64 + j * 16 + lm) * 64 + kk * 32 + quad * 8];
#pragma unroll
            for (int i = 0; i < 4; i++)
#pragma unroll
                for (int j = 0; j < 4; j++)
                    acc[i][j] = __builtin_amdgcn_mfma_f32_16x16x32_bf16(a[i], b[j], acc[i][j], 0, 0, 0);
        }
    }
#pragma unroll
    for (int j = 0; j < 4; j++) {
        int col = tile_n * 128 + wn * 64 + j * 16 + lm;
        float bias = b2[e * N + col];
#pragma unroll
        for (int i = 0; i < 4; i++)
#pragma unroll
            for (int r = 0; r < 4; r++) {
                int row = tile_m * 128 + wm * 64 + i * 16 + quad * 4 + r;
                int tok = tok_of_row[row];
                if (tok >= 0) {
                    float v = (acc[i][j][r] + bias) * gate_of_row[row];
                    out[(size_t)tok * N + col] = v;   // fp32 store
                }
            }
    }
}

extern "C" void kernel_launch(void* const* d_in, const int* in_sizes, int n_in,
                              void* d_out, int out_size, void* d_ws, size_t ws_size,
                              hipStream_t stream) {
    const float* x  = (const float*)d_in[0];
    const float* Wr = (const float*)d_in[1];
    const float* br = (const float*)d_in[2];
    const float* W1 = (const float*)d_in[3];
    const float* b1 = (const float*)d_in[4];
    const float* W2 = (const float*)d_in[5];
    const float* b2 = (const float*)d_in[6];
    float* out = (float*)d_out;
    char* ws = (char*)d_ws;

    // ws layout (bytes)
    int*    counts      = (int*)(ws + 0);       // 32 B (zeroed)
    int*    cursor      = (int*)(ws + 32);      // 32 B (zeroed)
    int*    pad_off     = (int*)(ws + 64);      // 32 B
    int*    tile_expert = (int*)(ws + 96);      // 288 B
    int*    expert_id   = (int*)(ws + 512);     // 32 KiB
    float*  gate        = (float*)(ws + 33280); // 32 KiB
    int*    tok_of_row  = (int*)(ws + 66048);   // 36 KiB (0xFF => -1)
    float*  gate_of_row = (float*)(ws + 102912);// 36 KiB
    bf16_t* hbuf        = (bf16_t*)(ws + 139776);    // 9216*2048*2 = 37,748,736
    bf16_t* W1t         = (bf16_t*)(ws + 37888512);  // 8*2048*1024*2 = 33,554,432
    bf16_t* W2t         = (bf16_t*)(ws + 71442944);  // 8*1024*2048*2 = 33,554,432
    bf16_t* xbf         = (bf16_t*)(ws + 104997376); // 8192*1024*2  = 16,777,216
    // total ~122 MB

    hipMemsetAsync(counts, 0, 64, stream);                       // counts + cursor
    hipMemsetAsync(tok_of_row, 0xFF, (MAXTILES * 128) * 4, stream);

    router_kernel<<<T_TOK / 4, 256, 0, stream>>>(x, Wr, br, expert_id, gate, counts);
    scan_kernel<<<1, 64, 0, stream>>>(counts, pad_off, tile_expert);
    scatter_kernel<<<T_TOK / 256, 256, 0, stream>>>(expert_id, gate, pad_off, cursor,
                                                    tok_of_row, gate_of_row);
    cvt_kernel<<<(T_TOK * DDIM) / (256 * 8), 256, 0, stream>>>(x, xbf);
    transpose_kernel<<<dim3(HDIM / 64, DDIM / 64, NEXP), 256, 0, stream>>>(W1, W1t, DDIM, HDIM);
    transpose_kernel<<<dim3(DDIM / 64, HDIM / 64, NEXP), 256, 0, stream>>>(W2, W2t, HDIM, DDIM);
    gemm1_kernel<<<dim3(HDIM / 128, MAXTILES), 256, 0, stream>>>(xbf, W1t, b1, tile_expert,
                                                                 tok_of_row, hbuf);
    gemm2_kernel<<<dim3(DDIM / 128, MAXTILES), 256, 0, stream>>>(hbuf, W2t, b2, tile_expert,
                                                                 tok_of_row, gate_of_row, out);
}